// Round 11
// baseline (177.208 us; speedup 1.0000x reference)
//
#include <hip/hip_runtime.h>
#include <hip/hip_bf16.h>
#include <stdint.h>
#include <stddef.h>

typedef __attribute__((ext_vector_type(8))) short short8;
typedef __attribute__((ext_vector_type(4))) float f32x4;
typedef __attribute__((ext_vector_type(16))) float f32x16;
typedef __attribute__((ext_vector_type(8))) unsigned short ushort8;

// global -> LDS direct copy, 16B per lane. LDS dest must be base + lane*16.
__device__ __forceinline__ void gload16(const void* g, void* l) {
    __builtin_amdgcn_global_load_lds(
        (__attribute__((address_space(1))) void*)g,
        (__attribute__((address_space(3))) void*)l,
        16, 0, 0);
}

// ---------------------------------------------------------------------------
__global__ void absmean_partial_k(const float* __restrict__ w,
                                  double* __restrict__ partials) {
    int tid = threadIdx.x;
    size_t base = (size_t)blockIdx.x * 8192 + (size_t)tid * 4;
    float s = 0.f;
#pragma unroll
    for (int i = 0; i < 8; ++i) {
        f32x4 v = *reinterpret_cast<const f32x4*>(w + base + (size_t)i * 1024);
        s += __builtin_fabsf(v.x) + __builtin_fabsf(v.y) +
             __builtin_fabsf(v.z) + __builtin_fabsf(v.w);
    }
    double d = (double)s;
#pragma unroll
    for (int off = 32; off > 0; off >>= 1) d += __shfl_down(d, off, 64);
    __shared__ double red[4];
    int lane = tid & 63, wid = tid >> 6;
    if (lane == 0) red[wid] = d;
    __syncthreads();
    if (tid == 0) partials[blockIdx.x] = red[0] + red[1] + red[2] + red[3];
}

__global__ void absmean_final_k(const double* __restrict__ partials,
                                float* __restrict__ sc, int nparts, int count) {
    int tid = threadIdx.x;
    double d = 0.0;
    for (int i = tid; i < nparts; i += 256) d += partials[i];
#pragma unroll
    for (int off = 32; off > 0; off >>= 1) d += __shfl_down(d, off, 64);
    __shared__ double red[4];
    int lane = tid & 63, wid = tid >> 6;
    if (lane == 0) red[wid] = d;
    __syncthreads();
    if (tid == 0) {
        double total = red[0] + red[1] + red[2] + red[3];
        float scale = (float)(total / (double)count);
        sc[0] = scale;
        sc[1] = scale + 1e-8f;
    }
}

__global__ void quantize_w_k(const float* __restrict__ w,
                             __hip_bfloat16* __restrict__ wq,
                             const float* __restrict__ sc) {
    float speps = sc[1];
    size_t i = ((size_t)blockIdx.x * 256 + threadIdx.x) * 8;
    f32x4 a = *reinterpret_cast<const f32x4*>(w + i);
    f32x4 b = *reinterpret_cast<const f32x4*>(w + i + 4);
    float v[8] = {a.x, a.y, a.z, a.w, b.x, b.y, b.z, b.w};
    ushort8 o;
#pragma unroll
    for (int j = 0; j < 8; ++j) {
        float t = v[j] / speps;
        t = fminf(fmaxf(t, -1.f), 1.f);
        float r = rintf(t);
        __hip_bfloat16 h = __float2bfloat16(r);
        o[j] = *reinterpret_cast<unsigned short*>(&h);
    }
    *reinterpret_cast<ushort8*>(wq + i) = o;
}

__global__ void cast_x_k(const float* __restrict__ x,
                         __hip_bfloat16* __restrict__ xb) {
    size_t i = ((size_t)blockIdx.x * 256 + threadIdx.x) * 8;
    f32x4 a = *reinterpret_cast<const f32x4*>(x + i);
    f32x4 b = *reinterpret_cast<const f32x4*>(x + i + 4);
    float v[8] = {a.x, a.y, a.z, a.w, b.x, b.y, b.z, b.w};
    ushort8 o;
#pragma unroll
    for (int j = 0; j < 8; ++j) {
        __hip_bfloat16 h = __float2bfloat16(v[j]);
        o[j] = *reinterpret_cast<unsigned short*>(&h);
    }
    *reinterpret_cast<ushort8*>(xb + i) = o;
}

// ---------------------------------------------------------------------------
// 256x256 8-phase GEMM, r10 skeleton (32x32x16 MFMA, spread staging, VM4x6
// ledger, 24 ds_read/K-tile) with the LDS swizzle widened 3->5 row bits:
//   slot ^= ((row&7)<<4) ^ (((row>>3)&3)<<5)
// Rationale: 32x32 fragments put lanes {l,l+8,l+16,l+24} (same lane&7, same
// swizzle term under the 3-bit scheme) on 4 DISTINCT rows -> 4-way slot
// collapse (measured 1.26e7 conflicts in r10). Folding row bits 3-4 into
// slot bits 5-6 makes those 4 rows hit 4 distinct slots; degeneracy <=2-way
// (free) under any lane-grouping. Involution, bits 4-6 only, both-sides.
#define BUF1 65536

__global__ __launch_bounds__(512, 2) void gemm8_k(
    const __hip_bfloat16* __restrict__ A,   // [M][K]
    const __hip_bfloat16* __restrict__ B,   // [N][K]
    float* __restrict__ C,                  // [M][N]
    const float* __restrict__ sc, int M, int N, int K) {
    extern __shared__ char smem[];

    int nwg = gridDim.x, wg = blockIdx.x, swz = wg;
    if ((nwg & 7) == 0) { int cpx = nwg >> 3; swz = (wg & 7) * cpx + (wg >> 3); }
    int nbn = N >> 8;
    int brow = (swz / nbn) << 8, bcol = (swz % nbn) << 8;

    int tid = threadIdx.x, lane = tid & 63, wave = tid >> 6;
    int wm2 = wave >> 2, wn4 = wave & 3;          // 2x4 wave grid in quadrant
    int l31 = lane & 31, l5 = lane >> 5;
    // 5-bit row swizzle: row bits 0-2 -> slot bits 4-6; row bits 3-4 -> 5-6
    int swl = ((lane & 7) << 4) ^ (((lane >> 3) & 3) << 5);

    // k-group byte slots within a 128B row (XOR folds swizzle; bits 4-6)
    int ks[4];
#pragma unroll
    for (int kg = 0; kg < 4; ++kg) ks[kg] = (kg * 32 + l5 * 16) ^ swl;

    // regions per buffer: A = [256 rows][128B] @0, B same @32768.
    // All quad/mb/wave row offsets are multiples of 32 -> row bits 0-4 = lane
    // bits, so swl is row-consistent everywhere.
    int abase0 = (wm2 * 64 + l31) * 128;          // A-half0 row base
    int abase1 = abase0 + 16384;                  // A-half1 (+128 rows)
    int bbase0 = 32768 + (wn4 * 32 + l31) * 128;  // B-half0
    int bbase1 = bbase0 + 16384;                  // B-half1

    // staging: dest byte d = tid*16 (linear); row(d) = tid>>3 within 64-row
    // sub-block; source logical slot = slot ^ ((row&7)<<4) ^ (((row>>3)&3)<<5)
    int sw_t = (((tid >> 3) & 7) << 4) ^ (((tid >> 6) & 3) << 5);
    int base_e = (tid * 16) ^ sw_t;
    int r0 = base_e >> 7;                         // 0..63
    int c0 = (base_e & 127) >> 1;                 // element col 0..63
    const __hip_bfloat16* sA = A + (size_t)(brow + r0) * K + c0;
    const __hip_bfloat16* sB = B + (size_t)(bcol + r0) * K + c0;
    size_t r64 = (size_t)64 * K, r128 = (size_t)128 * K;
    char* dA = smem + tid * 16;
    char* dB = smem + 32768 + tid * 16;

#define STG_A(BUF, H, KT) do { \
    const __hip_bfloat16* _s = sA + (size_t)(H) * r128 + (KT); \
    char* _d = dA + (BUF) + (H) * 16384; \
    gload16(_s, _d); gload16(_s + r64, _d + 8192); } while (0)
#define STG_B(BUF, H, KT) do { \
    const __hip_bfloat16* _s = sB + (size_t)(H) * r128 + (KT); \
    char* _d = dB + (BUF) + (H) * 16384; \
    gload16(_s, _d); gload16(_s + r64, _d + 8192); } while (0)

    f32x16 acc[4][2];   // [qm*2+qn][mb]  (2 m-blocks of 32 rows per quad)
#pragma unroll
    for (int q = 0; q < 4; ++q)
#pragma unroll
        for (int mb = 0; mb < 2; ++mb) acc[q][mb] = (f32x16)(0.f);

    short8 aq[2][4];    // A frags: [mb][kg]; A0 in p1-p2, A1 in p3-p4
    short8 bq0[4];      // B-half0 frags [kg] -- persist p1..p4
    short8 bq1[4];      // B-half1 frags [kg] -- live p2..p3

#define LDQ_A(BUF, ABASE) do { \
    _Pragma("unroll") for (int mb = 0; mb < 2; ++mb) \
    _Pragma("unroll") for (int kg = 0; kg < 4; ++kg) \
        aq[mb][kg] = *(const short8*)(smem + (BUF) + (ABASE) + mb * 4096 + ks[kg]); \
    } while (0)
#define LDQ_B(BUF, BBASE, DST) do { \
    _Pragma("unroll") for (int kg = 0; kg < 4; ++kg) \
        DST[kg] = *(const short8*)(smem + (BUF) + (BBASE) + ks[kg]); } while (0)
#define MM(Q, BQ) do { \
    __builtin_amdgcn_s_setprio(1); \
    _Pragma("unroll") for (int kg = 0; kg < 4; ++kg) \
    _Pragma("unroll") for (int mb = 0; mb < 2; ++mb) \
        acc[Q][mb] = __builtin_amdgcn_mfma_f32_32x32x16_bf16( \
            aq[mb][kg], BQ[kg], acc[Q][mb], 0, 0, 0); \
    __builtin_amdgcn_s_setprio(0); } while (0)
#define BAR __builtin_amdgcn_s_barrier()
#define LGKM asm volatile("s_waitcnt lgkmcnt(0)" ::: "memory")
#define VM4 asm volatile("s_waitcnt vmcnt(4)" ::: "memory")
#define VM2 asm volatile("s_waitcnt vmcnt(2)" ::: "memory")
#define VM0 asm volatile("s_waitcnt vmcnt(0)" ::: "memory")

    // prologue: tile0 -> b0, issue order A0,B0,B1,A1. VM4 forces A0,B0;
    // leaves {B1,A1} = 4 in flight = steady-state p1 entry invariant.
    STG_A(0, 0, 0); STG_B(0, 0, 0); STG_B(0, 1, 0); STG_A(0, 1, 0);
    VM4; BAR;

    int nit = K / 128 - 1;  // full iterations; last one peeled
    for (int it = 0; it < nit; ++it) {
        int kb1 = it * 128 + 64;    // tile 2it+1 -> b1 (read p5..p8)
        int kb0 = it * 128 + 128;   // tile 2it+2 -> b0 (read next iter)
        // p1: quad(0,0): aq=A0, bq0=B0 | stage b1.A0
        LDQ_A(0, abase0); LDQ_B(0, bbase0, bq0);
        STG_A(BUF1, 0, kb1);
        BAR; LGKM; MM(0, bq0); VM4; BAR;   // forces b0.B1 (for p2)
        // p2: quad(0,1): bq1=B1 | stage b1.B0
        LDQ_B(0, bbase1, bq1);
        STG_B(BUF1, 0, kb1);
        BAR; LGKM; MM(1, bq1); VM4; BAR;   // forces b0.A1 (for p3)
        // p3: quad(1,1): aq=A1 | stage b1.B1
        LDQ_A(0, abase1);
        STG_B(BUF1, 1, kb1);
        BAR; LGKM; MM(3, bq1); BAR;
        // p4: quad(1,0): pure MFMA | stage b1.A1
        STG_A(BUF1, 1, kb1);
        BAR; MM(2, bq0); VM4; BAR;         // forces b1.A0, b1.B0 (for p5)
        // p5: quad(0,0) of b1 | stage b0'.A0
        LDQ_A(BUF1, abase0); LDQ_B(BUF1, bbase0, bq0);
        STG_A(0, 0, kb0);
        BAR; LGKM; MM(0, bq0); VM4; BAR;   // forces b1.B1 (for p6)
        // p6: quad(0,1) | stage b0'.B0
        LDQ_B(BUF1, bbase1, bq1);
        STG_B(0, 0, kb0);
        BAR; LGKM; MM(1, bq1); VM4; BAR;   // forces b1.A1 (for p7)
        // p7: quad(1,1) | stage b0'.B1
        LDQ_A(BUF1, abase1);
        STG_B(0, 1, kb0);
        BAR; LGKM; MM(3, bq1); BAR;
        // p8: quad(1,0): pure MFMA | stage b0'.A1
        STG_A(0, 1, kb0);
        BAR; MM(2, bq0); VM4; BAR;         // forces b0'.A0, b0'.B0 (for p1')
    }
    // peeled last iteration (tiles 2*nit, 2*nit+1): stage b1 at p1-p4 only
    {
        int kb1 = nit * 128 + 64;
        LDQ_A(0, abase0); LDQ_B(0, bbase0, bq0);
        STG_A(BUF1, 0, kb1);
        BAR; LGKM; MM(0, bq0); VM4; BAR;   // forces b0.B1
        LDQ_B(0, bbase1, bq1);
        STG_B(BUF1, 0, kb1);
        BAR; LGKM; MM(1, bq1); VM4; BAR;   // forces b0.A1
        LDQ_A(0, abase1);
        STG_B(BUF1, 1, kb1);
        BAR; LGKM; MM(3, bq1); BAR;
        STG_A(BUF1, 1, kb1);
        BAR; MM(2, bq0); VM4; BAR;         // forces b1.A0, b1.B0
        LDQ_A(BUF1, abase0); LDQ_B(BUF1, bbase0, bq0);
        BAR; LGKM; MM(0, bq0); VM2; BAR;   // forces b1.B1
        LDQ_B(BUF1, bbase1, bq1);
        BAR; LGKM; MM(1, bq1); VM0; BAR;   // forces b1.A1
        LDQ_A(BUF1, abase1);
        BAR; LGKM; MM(3, bq1); BAR;
        BAR; MM(2, bq0);
    }

    // epilogue: C/D layout col=lane&31, row=(reg&3)+8*(reg>>2)+4*(lane>>5)
    float scale = sc[0];
#pragma unroll
    for (int qm = 0; qm < 2; ++qm)
#pragma unroll
        for (int qn = 0; qn < 2; ++qn)
#pragma unroll
            for (int mb = 0; mb < 2; ++mb)
#pragma unroll
                for (int r = 0; r < 16; ++r) {
                    int grow = brow + qm * 128 + wm2 * 64 + mb * 32 +
                               (r & 3) + ((r >> 2) * 8) + l5 * 4;
                    int gcol = bcol + qn * 128 + wn4 * 32 + l31;
                    C[(size_t)grow * N + gcol] =
                        acc[qm * 2 + qn][mb][r] * scale;
                }
}

// ---------------------------------------------------------------------------
__global__ void gemm_fallback_k(const float* __restrict__ X,
                                const float* __restrict__ W,
                                float* __restrict__ C,
                                const float* __restrict__ sc,
                                int M, int N, int K) {
    __shared__ float Xs[32][33];
    __shared__ float Ws[32][33];
    float speps = sc[1];
    int nbn = N / 32;
    int brow = (blockIdx.x / nbn) * 32;
    int bcol = (blockIdx.x % nbn) * 32;
    int tx = threadIdx.x & 31;
    int ty4 = threadIdx.x >> 5;
    float acc[4] = {0.f, 0.f, 0.f, 0.f};
    for (int kt = 0; kt < K; kt += 32) {
#pragma unroll
        for (int i = 0; i < 4; ++i) {
            int idx = threadIdx.x + i * 256;
            int r = idx >> 5, c = idx & 31;
            Xs[r][c] = X[(size_t)(brow + r) * K + kt + c];
            float wv = W[(size_t)(bcol + r) * K + kt + c];
            float t = wv / speps;
            t = fminf(fmaxf(t, -1.f), 1.f);
            Ws[r][c] = rintf(t);
        }
        __syncthreads();
#pragma unroll
        for (int kk = 0; kk < 32; ++kk) {
            float wv = Ws[tx][kk];
#pragma unroll
            for (int i = 0; i < 4; ++i) acc[i] += Xs[ty4 * 4 + i][kk] * wv;
        }
        __syncthreads();
    }
    float scale = sc[0];
#pragma unroll
    for (int i = 0; i < 4; ++i)
        C[(size_t)(brow + ty4 * 4 + i) * N + (bcol + tx)] = acc[i] * scale;
}

// ---------------------------------------------------------------------------
extern "C" void kernel_launch(void* const* d_in, const int* in_sizes, int n_in,
                              void* d_out, int out_size, void* d_ws,
                              size_t ws_size, hipStream_t stream) {
    const float* x = (const float*)d_in[0];   // [B,S,K] f32
    const float* w = (const float*)d_in[1];   // [N,K]   f32
    float* out = (float*)d_out;               // [B,S,N] f32

    const int K = 4096;
    const int N = 4096;
    int xn = in_sizes[0];                     // M*K
    int wn = in_sizes[1];                     // N*K
    int M = xn / K;

    const int NPART = 2048;
    size_t off_sc = (size_t)NPART * 8;
    size_t off_xb = off_sc + 64;
    size_t need = off_xb + ((size_t)xn + (size_t)wn) * 2;

    bool shape_ok = (M % 256 == 0) && (N % 256 == 0) && (K % 256 == 0);

    if (ws_size >= need && shape_ok) {
        double* partials = (double*)d_ws;
        float* sc = (float*)((char*)d_ws + off_sc);
        __hip_bfloat16* xb = (__hip_bfloat16*)((char*)d_ws + off_xb);
        __hip_bfloat16* wq = xb + xn;

        absmean_partial_k<<<NPART, 256, 0, stream>>>(w, partials);
        absmean_final_k<<<1, 256, 0, stream>>>(partials, sc, NPART, wn);
        quantize_w_k<<<wn / 2048, 256, 0, stream>>>(w, wq, sc);
        cast_x_k<<<xn / 2048, 256, 0, stream>>>(x, xb);

        hipFuncSetAttribute(reinterpret_cast<const void*>(gemm8_k),
                            hipFuncAttributeMaxDynamicSharedMemorySize, 131072);
        dim3 grid((M / 256) * (N / 256));
        gemm8_k<<<grid, 512, 131072, stream>>>(xb, wq, out, sc, M, N, K);
    } else {
        double* partials = (double*)d_out;
        float* sc = (float*)d_ws;
        absmean_partial_k<<<NPART, 256, 0, stream>>>(w, partials);
        absmean_final_k<<<1, 256, 0, stream>>>(partials, sc, NPART, wn);
        dim3 grid((M / 32) * (N / 32));
        gemm_fallback_k<<<grid, 256, 0, stream>>>(x, w, out, sc, M, N, K);
    }
}

// Round 12
// 163.439 us; speedup vs baseline: 1.0842x; 1.0842x over previous
//
#include <hip/hip_runtime.h>
#include <hip/hip_bf16.h>
#include <stdint.h>
#include <stddef.h>

typedef __attribute__((ext_vector_type(8))) short short8;
typedef __attribute__((ext_vector_type(4))) float f32x4;
typedef __attribute__((ext_vector_type(8))) unsigned short ushort8;

// global -> LDS direct copy, 16B per lane. LDS dest must be base + lane*16.
__device__ __forceinline__ void gload16(const void* g, void* l) {
    __builtin_amdgcn_global_load_lds(
        (__attribute__((address_space(1))) void*)g,
        (__attribute__((address_space(3))) void*)l,
        16, 0, 0);
}

// ---------------------------------------------------------------------------
__global__ void absmean_partial_k(const float* __restrict__ w,
                                  double* __restrict__ partials) {
    int tid = threadIdx.x;
    size_t base = (size_t)blockIdx.x * 8192 + (size_t)tid * 4;
    float s = 0.f;
#pragma unroll
    for (int i = 0; i < 8; ++i) {
        f32x4 v = *reinterpret_cast<const f32x4*>(w + base + (size_t)i * 1024);
        s += __builtin_fabsf(v.x) + __builtin_fabsf(v.y) +
             __builtin_fabsf(v.z) + __builtin_fabsf(v.w);
    }
    double d = (double)s;
#pragma unroll
    for (int off = 32; off > 0; off >>= 1) d += __shfl_down(d, off, 64);
    __shared__ double red[4];
    int lane = tid & 63, wid = tid >> 6;
    if (lane == 0) red[wid] = d;
    __syncthreads();
    if (tid == 0) partials[blockIdx.x] = red[0] + red[1] + red[2] + red[3];
}

__global__ void absmean_final_k(const double* __restrict__ partials,
                                float* __restrict__ sc, int nparts, int count) {
    int tid = threadIdx.x;
    double d = 0.0;
    for (int i = tid; i < nparts; i += 256) d += partials[i];
#pragma unroll
    for (int off = 32; off > 0; off >>= 1) d += __shfl_down(d, off, 64);
    __shared__ double red[4];
    int lane = tid & 63, wid = tid >> 6;
    if (lane == 0) red[wid] = d;
    __syncthreads();
    if (tid == 0) {
        double total = red[0] + red[1] + red[2] + red[3];
        float scale = (float)(total / (double)count);
        sc[0] = scale;
        sc[1] = scale + 1e-8f;
    }
}

__global__ void quantize_w_k(const float* __restrict__ w,
                             __hip_bfloat16* __restrict__ wq,
                             const float* __restrict__ sc) {
    float speps = sc[1];
    size_t i = ((size_t)blockIdx.x * 256 + threadIdx.x) * 8;
    f32x4 a = *reinterpret_cast<const f32x4*>(w + i);
    f32x4 b = *reinterpret_cast<const f32x4*>(w + i + 4);
    float v[8] = {a.x, a.y, a.z, a.w, b.x, b.y, b.z, b.w};
    ushort8 o;
#pragma unroll
    for (int j = 0; j < 8; ++j) {
        float t = v[j] / speps;
        t = fminf(fmaxf(t, -1.f), 1.f);
        float r = rintf(t);
        __hip_bfloat16 h = __float2bfloat16(r);
        o[j] = *reinterpret_cast<unsigned short*>(&h);
    }
    *reinterpret_cast<ushort8*>(wq + i) = o;
}

__global__ void cast_x_k(const float* __restrict__ x,
                         __hip_bfloat16* __restrict__ xb) {
    size_t i = ((size_t)blockIdx.x * 256 + threadIdx.x) * 8;
    f32x4 a = *reinterpret_cast<const f32x4*>(x + i);
    f32x4 b = *reinterpret_cast<const f32x4*>(x + i + 4);
    float v[8] = {a.x, a.y, a.z, a.w, b.x, b.y, b.z, b.w};
    ushort8 o;
#pragma unroll
    for (int j = 0; j < 8; ++j) {
        __hip_bfloat16 h = __float2bfloat16(v[j]);
        o[j] = *reinterpret_cast<unsigned short*>(&h);
    }
    *reinterpret_cast<ushort8*>(xb + i) = o;
}

// ---------------------------------------------------------------------------
// 256x256 8-phase GEMM, r8 base (16x16x32 MFMA, 0 bank conflicts, quad order
// (0,0),(0,1),(1,1),(1,0), 24 ds_read/K-tile, 64 operand VGPRs) with the
// staging RE-TIMED for deep prefetch: every half-slice staged 5-6 phases
// before first read (slots: p1,p2 finish b1; p3-p6 stage b0'; p7,p8 begin
// b1'), and counted waits reduced to TWO vmcnt(4) per iteration (ends of
// p4 and p8) -- m201's discipline. Ledger: entering p1 with 4 outstanding
// (b1.A0,B0); VM4@p4 forces all b1 (read p5-p8); VM4@p8 forces all b0'
// (read next p1-p3). W-A-R: every restage >=1 barrier after the region's
// last LDS read. 3-bit row-XOR swizzle (conflict-free at 16x16, r4/r8).
#define BUF1 65536

__global__ __launch_bounds__(512, 2) void gemm8_k(
    const __hip_bfloat16* __restrict__ A,   // [M][K]
    const __hip_bfloat16* __restrict__ B,   // [N][K]
    float* __restrict__ C,                  // [M][N]
    const float* __restrict__ sc, int M, int N, int K) {
    extern __shared__ char smem[];

    int nwg = gridDim.x, wg = blockIdx.x, swz = wg;
    if ((nwg & 7) == 0) { int cpx = nwg >> 3; swz = (wg & 7) * cpx + (wg >> 3); }
    int nbn = N >> 8;
    int brow = (swz / nbn) << 8, bcol = (swz % nbn) << 8;

    int tid = threadIdx.x, lane = tid & 63, wave = tid >> 6;
    int wm2 = wave >> 2, wn4 = wave & 3;          // 2x4 wave grid in quadrant
    int l15 = lane & 15, l16 = lane >> 4;
    int swl = (l15 & 7) << 4;                     // 3-bit row-XOR swizzle

    // regions per buffer: A = [256 rows][128B] @0, B same @32768.
    int aoffq0 = (wm2 * 64 + l15) * 128 + ((l16 * 16) ^ swl);
    int aoffq1 = aoffq0 + 16384;                  // A-half1 (+128 rows)
    int boffq0 = 32768 + (wn4 * 32 + l15) * 128 + ((l16 * 16) ^ swl);
    int boffq1 = boffq0 + 16384;                  // B-half1

    // staging: dest byte d = tid*16 (linear); source logical = d ^ ((row&7)<<4)
    int sw_t = ((tid >> 3) & 7) << 4;
    int base_e = (tid * 16) ^ sw_t;
    int r0 = base_e >> 7;                         // 0..63
    int c0 = (base_e & 127) >> 1;                 // element col 0..63
    const __hip_bfloat16* sA = A + (size_t)(brow + r0) * K + c0;
    const __hip_bfloat16* sB = B + (size_t)(bcol + r0) * K + c0;
    size_t r64 = (size_t)64 * K, r128 = (size_t)128 * K;
    char* dA = smem + tid * 16;
    char* dB = smem + 32768 + tid * 16;

#define STG_A(BUF, H, KT) do { \
    const __hip_bfloat16* _s = sA + (size_t)(H) * r128 + (KT); \
    char* _d = dA + (BUF) + (H) * 16384; \
    gload16(_s, _d); gload16(_s + r64, _d + 8192); } while (0)
#define STG_B(BUF, H, KT) do { \
    const __hip_bfloat16* _s = sB + (size_t)(H) * r128 + (KT); \
    char* _d = dB + (BUF) + (H) * 16384; \
    gload16(_s, _d); gload16(_s + r64, _d + 8192); } while (0)

    f32x4 acc[4][8];   // [qm*2+qn][m2*2+n2]
#pragma unroll
    for (int q = 0; q < 4; ++q)
#pragma unroll
        for (int f = 0; f < 8; ++f) acc[q][f] = (f32x4)(0.f);

    short8 aq[4][2];    // current A-half frags (A0 in p1-p2, A1 in p3-p4)
    short8 bq0[2][2];   // B-half0 frags -- persist p1..p4
    short8 bq1[2][2];   // B-half1 frags -- live p2..p3

#define LDQ_A(BUF, AOFF) do { \
    _Pragma("unroll") for (int m2 = 0; m2 < 4; ++m2) { \
        int _o = (AOFF) + m2 * 2048; \
        aq[m2][0] = *(const short8*)(smem + (BUF) + _o); \
        aq[m2][1] = *(const short8*)(smem + (BUF) + (_o ^ 64)); } } while (0)
#define LDQ_B(BUF, BOFF, DST) do { \
    _Pragma("unroll") for (int n2 = 0; n2 < 2; ++n2) { \
        int _o = (BOFF) + n2 * 2048; \
        DST[n2][0] = *(const short8*)(smem + (BUF) + _o); \
        DST[n2][1] = *(const short8*)(smem + (BUF) + (_o ^ 64)); } } while (0)
#define MM(Q, BQ) do { \
    __builtin_amdgcn_s_setprio(1); \
    _Pragma("unroll") for (int m2 = 0; m2 < 4; ++m2) \
    _Pragma("unroll") for (int n2 = 0; n2 < 2; ++n2) { \
        acc[Q][m2*2+n2] = __builtin_amdgcn_mfma_f32_16x16x32_bf16( \
            aq[m2][0], BQ[n2][0], acc[Q][m2*2+n2], 0, 0, 0); \
        acc[Q][m2*2+n2] = __builtin_amdgcn_mfma_f32_16x16x32_bf16( \
            aq[m2][1], BQ[n2][1], acc[Q][m2*2+n2], 0, 0, 0); } \
    __builtin_amdgcn_s_setprio(0); } while (0)
#define BAR __builtin_amdgcn_s_barrier()
#define LGKM asm volatile("s_waitcnt lgkmcnt(0)" ::: "memory")
#define VM4 asm volatile("s_waitcnt vmcnt(4)" ::: "memory")
#define VM0 asm volatile("s_waitcnt vmcnt(0)" ::: "memory")

    // prologue: b0 = slice0 {A0,B0,B1,A1} + b1 = slice1 {A0,B0} (6 STG).
    // VM4 forces all of b0; leaves b1.A0,B0 (4 loads) in flight = the
    // steady-state p1-entry invariant.
    STG_A(0, 0, 0); STG_B(0, 0, 0); STG_B(0, 1, 0); STG_A(0, 1, 0);
    STG_A(BUF1, 0, 64); STG_B(BUF1, 0, 64);
    VM4; BAR;

    int nit = K / 128 - 1;  // full iterations; last one peeled
    for (int it = 0; it < nit; ++it) {
        int kb1 = it * 128 + 64;    // slice 2it+1 -> b1 (read p5..p8)
        int kb0 = it * 128 + 128;   // slice 2it+2 -> b0 (read next iter)
        int kb1n = it * 128 + 192;  // slice 2it+3 -> b1 (read next iter)
        // p1: quad(0,0): aq=A0, bq0=B0 | stage b1.B1 (lag 5 -> p6)
        LDQ_A(0, aoffq0); LDQ_B(0, boffq0, bq0);
        STG_B(BUF1, 1, kb1);
        BAR; LGKM; MM(0, bq0); BAR;
        // p2: quad(0,1): bq1=B1 | stage b1.A1 (lag 5 -> p7)
        LDQ_B(0, boffq1, bq1);
        STG_A(BUF1, 1, kb1);
        BAR; LGKM; MM(1, bq1); BAR;
        // p3: quad(1,1): aq=A1 | stage b0'.A0 (lag 6 -> next p1)
        LDQ_A(0, aoffq1);
        STG_A(0, 0, kb0);
        BAR; LGKM; MM(3, bq1); BAR;
        // p4: quad(1,0): pure MFMA | stage b0'.B0 | WAIT: forces all b1
        STG_B(0, 0, kb0);
        BAR; MM(2, bq0); VM4; BAR;   // outstanding: b0'.A0, b0'.B0 only
        // p5: quad(0,0) of b1 | stage b0'.B1
        LDQ_A(BUF1, aoffq0); LDQ_B(BUF1, boffq0, bq0);
        STG_B(0, 1, kb0);
        BAR; LGKM; MM(0, bq0); BAR;
        // p6: quad(0,1) | stage b0'.A1
        LDQ_B(BUF1, boffq1, bq1);
        STG_A(0, 1, kb0);
        BAR; LGKM; MM(1, bq1); BAR;
        // p7: quad(1,1) | stage b1'.A0
        LDQ_A(BUF1, aoffq1);
        STG_A(BUF1, 0, kb1n);
        BAR; LGKM; MM(3, bq1); BAR;
        // p8: quad(1,0): pure MFMA | stage b1'.B0 | WAIT: forces all b0'
        STG_B(BUF1, 0, kb1n);
        BAR; MM(2, bq0); VM4; BAR;   // outstanding: b1'.A0, b1'.B0 only
    }
    // peeled last iteration (slices 2*nit, 2*nit+1): stage only b1.B1/A1
    {
        int kb1 = nit * 128 + 64;
        LDQ_A(0, aoffq0); LDQ_B(0, boffq0, bq0);
        STG_B(BUF1, 1, kb1);
        BAR; LGKM; MM(0, bq0); BAR;
        LDQ_B(0, boffq1, bq1);
        STG_A(BUF1, 1, kb1);
        BAR; LGKM; MM(1, bq1); BAR;
        LDQ_A(0, aoffq1);
        BAR; LGKM; MM(3, bq1); BAR;
        BAR; MM(2, bq0); VM0; BAR;   // drain: all of b1 landed
        LDQ_A(BUF1, aoffq0); LDQ_B(BUF1, boffq0, bq0);
        BAR; LGKM; MM(0, bq0); BAR;
        LDQ_B(BUF1, boffq1, bq1);
        BAR; LGKM; MM(1, bq1); BAR;
        LDQ_A(BUF1, aoffq1);
        BAR; LGKM; MM(3, bq1); BAR;
        BAR; MM(2, bq0);
    }

    float scale = sc[0];
#pragma unroll
    for (int qm = 0; qm < 2; ++qm)
#pragma unroll
        for (int qn = 0; qn < 2; ++qn)
#pragma unroll
            for (int m2 = 0; m2 < 4; ++m2)
#pragma unroll
                for (int n2 = 0; n2 < 2; ++n2)
#pragma unroll
                    for (int r = 0; r < 4; ++r) {
                        int grow = brow + qm * 128 + wm2 * 64 + m2 * 16 + l16 * 4 + r;
                        int gcol = bcol + qn * 128 + wn4 * 32 + n2 * 16 + l15;
                        C[(size_t)grow * N + gcol] =
                            acc[qm * 2 + qn][m2 * 2 + n2][r] * scale;
                    }
}

// ---------------------------------------------------------------------------
__global__ void gemm_fallback_k(const float* __restrict__ X,
                                const float* __restrict__ W,
                                float* __restrict__ C,
                                const float* __restrict__ sc,
                                int M, int N, int K) {
    __shared__ float Xs[32][33];
    __shared__ float Ws[32][33];
    float speps = sc[1];
    int nbn = N / 32;
    int brow = (blockIdx.x / nbn) * 32;
    int bcol = (blockIdx.x % nbn) * 32;
    int tx = threadIdx.x & 31;
    int ty4 = threadIdx.x >> 5;
    float acc[4] = {0.f, 0.f, 0.f, 0.f};
    for (int kt = 0; kt < K; kt += 32) {
#pragma unroll
        for (int i = 0; i < 4; ++i) {
            int idx = threadIdx.x + i * 256;
            int r = idx >> 5, c = idx & 31;
            Xs[r][c] = X[(size_t)(brow + r) * K + kt + c];
            float wv = W[(size_t)(bcol + r) * K + kt + c];
            float t = wv / speps;
            t = fminf(fmaxf(t, -1.f), 1.f);
            Ws[r][c] = rintf(t);
        }
        __syncthreads();
#pragma unroll
        for (int kk = 0; kk < 32; ++kk) {
            float wv = Ws[tx][kk];
#pragma unroll
            for (int i = 0; i < 4; ++i) acc[i] += Xs[ty4 * 4 + i][kk] * wv;
        }
        __syncthreads();
    }
    float scale = sc[0];
#pragma unroll
    for (int i = 0; i < 4; ++i)
        C[(size_t)(brow + ty4 * 4 + i) * N + (bcol + tx)] = acc[i] * scale;
}

// ---------------------------------------------------------------------------
extern "C" void kernel_launch(void* const* d_in, const int* in_sizes, int n_in,
                              void* d_out, int out_size, void* d_ws,
                              size_t ws_size, hipStream_t stream) {
    const float* x = (const float*)d_in[0];   // [B,S,K] f32
    const float* w = (const float*)d_in[1];   // [N,K]   f32
    float* out = (float*)d_out;               // [B,S,N] f32

    const int K = 4096;
    const int N = 4096;
    int xn = in_sizes[0];                     // M*K
    int wn = in_sizes[1];                     // N*K
    int M = xn / K;

    const int NPART = 2048;
    size_t off_sc = (size_t)NPART * 8;
    size_t off_xb = off_sc + 64;
    size_t need = off_xb + ((size_t)xn + (size_t)wn) * 2;

    bool shape_ok = (M % 256 == 0) && (N % 256 == 0) && (K % 256 == 0);

    if (ws_size >= need && shape_ok) {
        double* partials = (double*)d_ws;
        float* sc = (float*)((char*)d_ws + off_sc);
        __hip_bfloat16* xb = (__hip_bfloat16*)((char*)d_ws + off_xb);
        __hip_bfloat16* wq = xb + xn;

        absmean_partial_k<<<NPART, 256, 0, stream>>>(w, partials);
        absmean_final_k<<<1, 256, 0, stream>>>(partials, sc, NPART, wn);
        quantize_w_k<<<wn / 2048, 256, 0, stream>>>(w, wq, sc);
        cast_x_k<<<xn / 2048, 256, 0, stream>>>(x, xb);

        hipFuncSetAttribute(reinterpret_cast<const void*>(gemm8_k),
                            hipFuncAttributeMaxDynamicSharedMemorySize, 131072);
        dim3 grid((M / 256) * (N / 256));
        gemm8_k<<<grid, 512, 131072, stream>>>(xb, wq, out, sc, M, N, K);
    } else {
        double* partials = (double*)d_out;
        float* sc = (float*)d_ws;
        absmean_partial_k<<<NPART, 256, 0, stream>>>(w, partials);
        absmean_final_k<<<1, 256, 0, stream>>>(partials, sc, NPART, wn);
        dim3 grid((M / 32) * (N / 32));
        gemm_fallback_k<<<grid, 256, 0, stream>>>(x, w, out, sc, M, N, K);
    }
}

// Round 13
// 119.726 us; speedup vs baseline: 1.4801x; 1.3651x over previous
//
#include <hip/hip_runtime.h>
#include <hip/hip_bf16.h>
#include <stdint.h>
#include <stddef.h>

typedef __attribute__((ext_vector_type(4))) int int4v;
typedef __attribute__((ext_vector_type(4))) float f32x4;

// global -> LDS direct copy, 16B per lane. LDS dest must be base + lane*16.
__device__ __forceinline__ void gload16(const void* g, void* l) {
    __builtin_amdgcn_global_load_lds(
        (__attribute__((address_space(1))) void*)g,
        (__attribute__((address_space(3))) void*)l,
        16, 0, 0);
}

// ---------------------------------------------------------------------------
__global__ void absmean_partial_k(const float* __restrict__ w,
                                  double* __restrict__ partials) {
    int tid = threadIdx.x;
    size_t base = (size_t)blockIdx.x * 8192 + (size_t)tid * 4;
    float s = 0.f;
#pragma unroll
    for (int i = 0; i < 8; ++i) {
        f32x4 v = *reinterpret_cast<const f32x4*>(w + base + (size_t)i * 1024);
        s += __builtin_fabsf(v.x) + __builtin_fabsf(v.y) +
             __builtin_fabsf(v.z) + __builtin_fabsf(v.w);
    }
    double d = (double)s;
#pragma unroll
    for (int off = 32; off > 0; off >>= 1) d += __shfl_down(d, off, 64);
    __shared__ double red[4];
    int lane = tid & 63, wid = tid >> 6;
    if (lane == 0) red[wid] = d;
    __syncthreads();
    if (tid == 0) partials[blockIdx.x] = red[0] + red[1] + red[2] + red[3];
}

__global__ void absmean_final_k(const double* __restrict__ partials,
                                float* __restrict__ sc, int nparts, int count) {
    int tid = threadIdx.x;
    double d = 0.0;
    for (int i = tid; i < nparts; i += 256) d += partials[i];
#pragma unroll
    for (int off = 32; off > 0; off >>= 1) d += __shfl_down(d, off, 64);
    __shared__ double red[4];
    int lane = tid & 63, wid = tid >> 6;
    if (lane == 0) red[wid] = d;
    __syncthreads();
    if (tid == 0) {
        double total = red[0] + red[1] + red[2] + red[3];
        float scale = (float)(total / (double)count);
        sc[0] = scale;
        sc[1] = scale + 1e-8f;
    }
}

// Quantize w -> ternary int8 {-1,0,1} (EXACT). 16 elems/thread.
__global__ void quantize_w_i8_k(const float* __restrict__ w,
                                char* __restrict__ wq,
                                const float* __restrict__ sc) {
    float speps = sc[1];
    size_t base = ((size_t)blockIdx.x * 256 + threadIdx.x) * 16;
    int p[4] = {0, 0, 0, 0};
#pragma unroll
    for (int i = 0; i < 4; ++i) {
        f32x4 v = *reinterpret_cast<const f32x4*>(w + base + i * 4);
        float e[4] = {v.x, v.y, v.z, v.w};
#pragma unroll
        for (int j = 0; j < 4; ++j) {
            float t = e[j] / speps;
            t = fminf(fmaxf(t, -1.f), 1.f);
            int q = ((int)rintf(t)) & 0xFF;
            p[i] |= q << (j * 8);
        }
    }
    int4v o = {p[0], p[1], p[2], p[3]};
    *reinterpret_cast<int4v*>(wq + base) = o;
}

// Per-row max|x|. One block per row (K=4096, 256 threads x 16 elems).
__global__ void rowmax_x_k(const float* __restrict__ x,
                           float* __restrict__ maxv, int K) {
    int tid = threadIdx.x;
    size_t base = (size_t)blockIdx.x * K + (size_t)tid * 4;
    float m = 0.f;
#pragma unroll
    for (int i = 0; i < 4; ++i) {
        f32x4 v = *reinterpret_cast<const f32x4*>(x + base + (size_t)i * 1024);
        m = fmaxf(m, fmaxf(fmaxf(__builtin_fabsf(v.x), __builtin_fabsf(v.y)),
                           fmaxf(__builtin_fabsf(v.z), __builtin_fabsf(v.w))));
    }
#pragma unroll
    for (int off = 32; off > 0; off >>= 1) m = fmaxf(m, __shfl_down(m, off, 64));
    __shared__ float red[4];
    int lane = tid & 63, wid = tid >> 6;
    if (lane == 0) red[wid] = m;
    __syncthreads();
    if (tid == 0)
        maxv[blockIdx.x] = fmaxf(fmaxf(red[0], red[1]), fmaxf(red[2], red[3]));
}

// Quantize x -> int8 with per-row scale sx = rowmax/127. 16 elems/thread.
__global__ void quantize_x_i8_k(const float* __restrict__ x,
                                char* __restrict__ xq,
                                const float* __restrict__ maxv, int K) {
    int row = blockIdx.x;
    float mv = maxv[row];
    float recip = (mv > 0.f) ? (127.f / mv) : 0.f;
    size_t base = (size_t)row * K + (size_t)threadIdx.x * 16;
    int p[4] = {0, 0, 0, 0};
#pragma unroll
    for (int i = 0; i < 4; ++i) {
        f32x4 v = *reinterpret_cast<const f32x4*>(x + base + i * 4);
        float e[4] = {v.x, v.y, v.z, v.w};
#pragma unroll
        for (int j = 0; j < 4; ++j) {
            int q = ((int)rintf(e[j] * recip)) & 0xFF;
            p[i] |= q << (j * 8);
        }
    }
    int4v o = {p[0], p[1], p[2], p[3]};
    *reinterpret_cast<int4v*>(xq + base) = o;
}

// ---------------------------------------------------------------------------
// 256x256 8-phase GEMM, i8 transmutation of the r12 kernel: identical LDS
// byte-layout (128B rows = 128 i8), identical 3-bit row-XOR swizzle,
// identical staging/ledger (deep prefetch, 2x vmcnt(4)/iter), identical
// phases -- but mfma_i32_16x16x64_i8 (2x rate, exact i32 accumulate) and
// K-tile = 256 elements per iteration (16 iters instead of 32).
// Epilogue: C = acc_i32 * rowscale(maxv[row]*s/127).
#define BUF1 65536

__global__ __launch_bounds__(512, 2) void gemm8_k(
    const char* __restrict__ A,   // [M][K] i8
    const char* __restrict__ B,   // [N][K] i8
    float* __restrict__ C,        // [M][N]
    const float* __restrict__ sc, const float* __restrict__ maxv,
    int M, int N, int K) {
    extern __shared__ char smem[];

    int nwg = gridDim.x, wg = blockIdx.x, swz = wg;
    if ((nwg & 7) == 0) { int cpx = nwg >> 3; swz = (wg & 7) * cpx + (wg >> 3); }
    int nbn = N >> 8;
    int brow = (swz / nbn) << 8, bcol = (swz % nbn) << 8;

    int tid = threadIdx.x, lane = tid & 63, wave = tid >> 6;
    int wm2 = wave >> 2, wn4 = wave & 3;          // 2x4 wave grid in quadrant
    int l15 = lane & 15, l16 = lane >> 4;
    int swl = (l15 & 7) << 4;                     // 3-bit row-XOR swizzle

    // regions per buffer: A = [256 rows][128B] @0, B same @32768.
    // i8 fragment: lane row = l&15, k-slot = (l>>4)*16B; k-half = ^64 (bit 6).
    int aoffq0 = (wm2 * 64 + l15) * 128 + ((l16 * 16) ^ swl);
    int aoffq1 = aoffq0 + 16384;                  // A-half1 (+128 rows)
    int boffq0 = 32768 + (wn4 * 32 + l15) * 128 + ((l16 * 16) ^ swl);
    int boffq1 = boffq0 + 16384;                  // B-half1

    // staging: dest byte d = tid*16 (linear); source logical = d ^ ((row&7)<<4)
    int sw_t = ((tid >> 3) & 7) << 4;
    int base_e = (tid * 16) ^ sw_t;
    int r0 = base_e >> 7;                         // row 0..63
    int c0 = base_e & 127;                        // i8 col 0..127
    const char* sA = A + (size_t)(brow + r0) * K + c0;
    const char* sB = B + (size_t)(bcol + r0) * K + c0;
    size_t r64 = (size_t)64 * K, r128 = (size_t)128 * K;
    char* dA = smem + tid * 16;
    char* dB = smem + 32768 + tid * 16;

#define STG_A(BUF, H, KT) do { \
    const char* _s = sA + (size_t)(H) * r128 + (KT); \
    char* _d = dA + (BUF) + (H) * 16384; \
    gload16(_s, _d); gload16(_s + r64, _d + 8192); } while (0)
#define STG_B(BUF, H, KT) do { \
    const char* _s = sB + (size_t)(H) * r128 + (KT); \
    char* _d = dB + (BUF) + (H) * 16384; \
    gload16(_s, _d); gload16(_s + r64, _d + 8192); } while (0)

    int4v acc[4][8];   // [qm*2+qn][m2*2+n2], i32x4 accumulators
#pragma unroll
    for (int q = 0; q < 4; ++q)
#pragma unroll
        for (int f = 0; f < 8; ++f) acc[q][f] = (int4v)(0);

    int4v aq[4][2];    // current A-half frags (A0 in p1-p2, A1 in p3-p4)
    int4v bq0[2][2];   // B-half0 frags -- persist p1..p4
    int4v bq1[2][2];   // B-half1 frags -- live p2..p3

#define LDQ_A(BUF, AOFF) do { \
    _Pragma("unroll") for (int m2 = 0; m2 < 4; ++m2) { \
        int _o = (AOFF) + m2 * 2048; \
        aq[m2][0] = *(const int4v*)(smem + (BUF) + _o); \
        aq[m2][1] = *(const int4v*)(smem + (BUF) + (_o ^ 64)); } } while (0)
#define LDQ_B(BUF, BOFF, DST) do { \
    _Pragma("unroll") for (int n2 = 0; n2 < 2; ++n2) { \
        int _o = (BOFF) + n2 * 2048; \
        DST[n2][0] = *(const int4v*)(smem + (BUF) + _o); \
        DST[n2][1] = *(const int4v*)(smem + (BUF) + (_o ^ 64)); } } while (0)
#define MM(Q, BQ) do { \
    __builtin_amdgcn_s_setprio(1); \
    _Pragma("unroll") for (int m2 = 0; m2 < 4; ++m2) \
    _Pragma("unroll") for (int n2 = 0; n2 < 2; ++n2) { \
        acc[Q][m2*2+n2] = __builtin_amdgcn_mfma_i32_16x16x64_i8( \
            aq[m2][0], BQ[n2][0], acc[Q][m2*2+n2], 0, 0, 0); \
        acc[Q][m2*2+n2] = __builtin_amdgcn_mfma_i32_16x16x64_i8( \
            aq[m2][1], BQ[n2][1], acc[Q][m2*2+n2], 0, 0, 0); } \
    __builtin_amdgcn_s_setprio(0); } while (0)
#define BAR __builtin_amdgcn_s_barrier()
#define LGKM asm volatile("s_waitcnt lgkmcnt(0)" ::: "memory")
#define VM4 asm volatile("s_waitcnt vmcnt(4)" ::: "memory")
#define VM0 asm volatile("s_waitcnt vmcnt(0)" ::: "memory")

    // prologue: b0 = slice0 {A0,B0,B1,A1} + b1 = slice1 {A0,B0} (6 STG).
    // VM4 forces all of b0; leaves b1.A0,B0 in flight (p1-entry invariant).
    STG_A(0, 0, 0); STG_B(0, 0, 0); STG_B(0, 1, 0); STG_A(0, 1, 0);
    STG_A(BUF1, 0, 128); STG_B(BUF1, 0, 128);
    VM4; BAR;

    int nit = K / 256 - 1;  // full iterations; last one peeled
    for (int it = 0; it < nit; ++it) {
        int kb1 = it * 256 + 128;    // slice 2it+1 -> b1 (read p5..p8)
        int kb0 = it * 256 + 256;    // slice 2it+2 -> b0 (read next iter)
        int kb1n = it * 256 + 384;   // slice 2it+3 -> b1 (read next iter)
        // p1: quad(0,0): aq=A0, bq0=B0 | stage b1.B1 (lag 5 -> p6)
        LDQ_A(0, aoffq0); LDQ_B(0, boffq0, bq0);
        STG_B(BUF1, 1, kb1);
        BAR; LGKM; MM(0, bq0); BAR;
        // p2: quad(0,1): bq1=B1 | stage b1.A1 (lag 5 -> p7)
        LDQ_B(0, boffq1, bq1);
        STG_A(BUF1, 1, kb1);
        BAR; LGKM; MM(1, bq1); BAR;
        // p3: quad(1,1): aq=A1 | stage b0'.A0 (lag 6 -> next p1)
        LDQ_A(0, aoffq1);
        STG_A(0, 0, kb0);
        BAR; LGKM; MM(3, bq1); BAR;
        // p4: quad(1,0): pure MFMA | stage b0'.B0 | WAIT: forces all b1
        STG_B(0, 0, kb0);
        BAR; MM(2, bq0); VM4; BAR;   // outstanding: b0'.A0, b0'.B0 only
        // p5: quad(0,0) of b1 | stage b0'.B1
        LDQ_A(BUF1, aoffq0); LDQ_B(BUF1, boffq0, bq0);
        STG_B(0, 1, kb0);
        BAR; LGKM; MM(0, bq0); BAR;
        // p6: quad(0,1) | stage b0'.A1
        LDQ_B(BUF1, boffq1, bq1);
        STG_A(0, 1, kb0);
        BAR; LGKM; MM(1, bq1); BAR;
        // p7: quad(1,1) | stage b1'.A0
        LDQ_A(BUF1, aoffq1);
        STG_A(BUF1, 0, kb1n);
        BAR; LGKM; MM(3, bq1); BAR;
        // p8: quad(1,0): pure MFMA | stage b1'.B0 | WAIT: forces all b0'
        STG_B(BUF1, 0, kb1n);
        BAR; MM(2, bq0); VM4; BAR;   // outstanding: b1'.A0, b1'.B0 only
    }
    // peeled last iteration (slices 2*nit, 2*nit+1): stage only b1.B1/A1
    {
        int kb1 = nit * 256 + 128;
        LDQ_A(0, aoffq0); LDQ_B(0, boffq0, bq0);
        STG_B(BUF1, 1, kb1);
        BAR; LGKM; MM(0, bq0); BAR;
        LDQ_B(0, boffq1, bq1);
        STG_A(BUF1, 1, kb1);
        BAR; LGKM; MM(1, bq1); BAR;
        LDQ_A(0, aoffq1);
        BAR; LGKM; MM(3, bq1); BAR;
        BAR; MM(2, bq0); VM0; BAR;   // drain: all of b1 landed
        LDQ_A(BUF1, aoffq0); LDQ_B(BUF1, boffq0, bq0);
        BAR; LGKM; MM(0, bq0); BAR;
        LDQ_B(BUF1, boffq1, bq1);
        BAR; LGKM; MM(1, bq1); BAR;
        LDQ_A(BUF1, aoffq1);
        BAR; LGKM; MM(3, bq1); BAR;
        BAR; MM(2, bq0);
    }

    // epilogue: C = acc_i32 * (maxv[row] * s / 127)
    float s127 = sc[0] * (1.0f / 127.0f);
#pragma unroll
    for (int qm = 0; qm < 2; ++qm)
#pragma unroll
        for (int m2 = 0; m2 < 4; ++m2)
#pragma unroll
            for (int r = 0; r < 4; ++r) {
                int grow = brow + qm * 128 + wm2 * 64 + m2 * 16 + l16 * 4 + r;
                float rs = maxv[grow] * s127;
#pragma unroll
                for (int qn = 0; qn < 2; ++qn)
#pragma unroll
                    for (int n2 = 0; n2 < 2; ++n2) {
                        int gcol = bcol + qn * 128 + wn4 * 32 + n2 * 16 + l15;
                        C[(size_t)grow * N + gcol] =
                            (float)acc[qm * 2 + qn][m2 * 2 + n2][r] * rs;
                    }
            }
}

// ---------------------------------------------------------------------------
// Fallback: fused f32 tile GEMM with on-the-fly quantization (tiny-ws path).
__global__ void gemm_fallback_k(const float* __restrict__ X,
                                const float* __restrict__ W,
                                float* __restrict__ C,
                                const float* __restrict__ sc,
                                int M, int N, int K) {
    __shared__ float Xs[32][33];
    __shared__ float Ws[32][33];
    float speps = sc[1];
    int nbn = N / 32;
    int brow = (blockIdx.x / nbn) * 32;
    int bcol = (blockIdx.x % nbn) * 32;
    int tx = threadIdx.x & 31;
    int ty4 = threadIdx.x >> 5;
    float acc[4] = {0.f, 0.f, 0.f, 0.f};
    for (int kt = 0; kt < K; kt += 32) {
#pragma unroll
        for (int i = 0; i < 4; ++i) {
            int idx = threadIdx.x + i * 256;
            int r = idx >> 5, c = idx & 31;
            Xs[r][c] = X[(size_t)(brow + r) * K + kt + c];
            float wv = W[(size_t)(bcol + r) * K + kt + c];
            float t = wv / speps;
            t = fminf(fmaxf(t, -1.f), 1.f);
            Ws[r][c] = rintf(t);
        }
        __syncthreads();
#pragma unroll
        for (int kk = 0; kk < 32; ++kk) {
            float wv = Ws[tx][kk];
#pragma unroll
            for (int i = 0; i < 4; ++i) acc[i] += Xs[ty4 * 4 + i][kk] * wv;
        }
        __syncthreads();
    }
    float scale = sc[0];
#pragma unroll
    for (int i = 0; i < 4; ++i)
        C[(size_t)(brow + ty4 * 4 + i) * N + (bcol + tx)] = acc[i] * scale;
}

// ---------------------------------------------------------------------------
extern "C" void kernel_launch(void* const* d_in, const int* in_sizes, int n_in,
                              void* d_out, int out_size, void* d_ws,
                              size_t ws_size, hipStream_t stream) {
    const float* x = (const float*)d_in[0];   // [B,S,K] f32
    const float* w = (const float*)d_in[1];   // [N,K]   f32
    float* out = (float*)d_out;               // [B,S,N] f32

    const int K = 4096;
    const int N = 4096;
    int xn = in_sizes[0];                     // M*K
    int wn = in_sizes[1];                     // N*K
    int M = xn / K;

    const int NPART = 2048;
    size_t off_sc = (size_t)NPART * 8;        // 16384
    size_t off_mx = off_sc + 64;              // maxv: M floats
    size_t off_xq = off_mx + (size_t)M * 4;
    off_xq = (off_xq + 63) & ~(size_t)63;
    size_t need = off_xq + (size_t)xn + (size_t)wn;  // i8 buffers

    bool shape_ok = (M % 256 == 0) && (N % 256 == 0) && (K % 256 == 0) &&
                    (K >= 512);

    if (ws_size >= need && shape_ok) {
        double* partials = (double*)d_ws;
        float* sc = (float*)((char*)d_ws + off_sc);
        float* maxv = (float*)((char*)d_ws + off_mx);
        char* xq = (char*)d_ws + off_xq;
        char* wq = xq + xn;

        absmean_partial_k<<<NPART, 256, 0, stream>>>(w, partials);
        absmean_final_k<<<1, 256, 0, stream>>>(partials, sc, NPART, wn);
        quantize_w_i8_k<<<wn / 4096, 256, 0, stream>>>(w, wq, sc);
        rowmax_x_k<<<M, 256, 0, stream>>>(x, maxv, K);
        quantize_x_i8_k<<<M, 256, 0, stream>>>(x, xq, maxv, K);

        hipFuncSetAttribute(reinterpret_cast<const void*>(gemm8_k),
                            hipFuncAttributeMaxDynamicSharedMemorySize, 131072);
        dim3 grid((M / 256) * (N / 256));
        gemm8_k<<<grid, 512, 131072, stream>>>(xq, wq, out, sc, maxv, M, N, K);
    } else {
        double* partials = (double*)d_out;
        float* sc = (float*)d_ws;
        absmean_partial_k<<<NPART, 256, 0, stream>>>(w, partials);
        absmean_final_k<<<1, 256, 0, stream>>>(partials, sc, NPART, wn);
        dim3 grid((M / 32) * (N / 32));
        gemm_fallback_k<<<grid, 256, 0, stream>>>(x, w, out, sc, M, N, K);
    }
}